// Round 2
// baseline (797.678 us; speedup 1.0000x reference)
//
#include <hip/hip_runtime.h>
#include <cstdint>

// ---------------------------------------------------------------------------
// GatedMLP: out = relu(relu(x@W1^T+b1) gated-blocksum @ W2^T + b2) @ W3^T
// N=4096, IN=1024, D=2048, G=8, 2D=4096, OUT=1024
// Strategy: bucket rows by gate -> permuted-row GEMMs in bf16 MFMA.
// (Resubmission of round-1 kernel: round-1 bench was an infra failure,
//  kernel never ran.)
// ---------------------------------------------------------------------------

#define NP 5120       // padded row space: 4096 + 8*128 slack
#define NROWT 40      // NP / 128
#define NROWS 4096
#define GATES 8

typedef short short8 __attribute__((ext_vector_type(8)));
typedef float f32x4 __attribute__((ext_vector_type(4)));

constexpr int BM = 128, BN = 128, BK = 32;
constexpr int LDSW = 40;   // 32 + 8 bf16 pad -> conflict-free ds_read_b128

__device__ __forceinline__ unsigned short f2b(float f) {
    __bf16 h = (__bf16)f;               // v_cvt_pk_bf16_f32 pairs via compiler
    return __builtin_bit_cast(unsigned short, h);
}

// ---------------------------------------------------------------------------
// Kernel 0: bucket rows by gate id into padded segments
// ---------------------------------------------------------------------------
__global__ void bucket_kernel(const int* __restrict__ gid,
                              int* __restrict__ perm,
                              int* __restrict__ tile_gate)
{
    __shared__ int cnt[GATES], pstart[GATES], cur[GATES];
    const int t = threadIdx.x;
    if (t < GATES) cnt[t] = 0;
    __syncthreads();
    for (int i = t; i < NROWS; i += 256) atomicAdd(&cnt[gid[i]], 1);
    __syncthreads();
    if (t == 0) {
        int off = 0;
        for (int g = 0; g < GATES; g++) {
            pstart[g] = off;
            cur[g] = 0;
            off += (cnt[g] + 127) & ~127;
        }
    }
    __syncthreads();
    for (int i = t; i < NP; i += 256) perm[i] = -1;
    if (t < NROWT) {
        int r0 = t * 128;
        int tg = 0;
        for (int g = 0; g < GATES; g++) {
            int pc = (cnt[g] + 127) & ~127;
            if (r0 >= pstart[g] && r0 < pstart[g] + pc) tg = g;
        }
        tile_gate[t] = tg;
    }
    __syncthreads();   // perm init complete before scatter
    for (int i = t; i < NROWS; i += 256) {
        int g = gid[i];
        int p = atomicAdd(&cur[g], 1);
        perm[pstart[g] + p] = i;
    }
}

// ---------------------------------------------------------------------------
// Layer 1: s_perm[r] = 0.9*relu(x[perm[r]]@W1_gate^T + b1_g)
//                    +     relu(x[perm[r]]@W1_shared^T + b1_sh)       (bf16)
// grid = (4096/BN=32, NROWT=40), block = 256 (4 waves, 2x2)
// ---------------------------------------------------------------------------
__global__ __launch_bounds__(256, 2)
void l1_kernel(const float* __restrict__ x,
               const float* __restrict__ W1,
               const float* __restrict__ b1,
               const int* __restrict__ perm,
               const int* __restrict__ tile_gate,
               unsigned short* __restrict__ s_out)
{
    __shared__ __align__(16) unsigned short As[BM][LDSW];
    __shared__ __align__(16) unsigned short Bg[BN][LDSW];
    __shared__ __align__(16) unsigned short Bs[BN][LDSW];

    const int t = threadIdx.x;
    const int rbase = blockIdx.y * BM;
    const int cbase = blockIdx.x * BN;
    const int gate = tile_gate[blockIdx.y];

    const int srow_t = t >> 3;          // 0..31
    const int scol   = (t & 7) * 4;     // 0,4,...,28

    int grow[4];
#pragma unroll
    for (int rr = 0; rr < 4; rr++) grow[rr] = perm[rbase + rr * 32 + srow_t];

    const float* Bgp = W1 + ((size_t)gate * 4096 + cbase) * 1024;
    const float* Bsp = W1 + ((size_t)GATES * 4096 + cbase) * 1024;

    f32x4 accg[4][4], accs[4][4];
#pragma unroll
    for (int m = 0; m < 4; m++)
#pragma unroll
        for (int n = 0; n < 4; n++) {
            accg[m][n] = (f32x4){0.f, 0.f, 0.f, 0.f};
            accs[m][n] = (f32x4){0.f, 0.f, 0.f, 0.f};
        }

    const int lane = t & 63;
    const int wid  = t >> 6;
    const int wr = wid >> 1, wc = wid & 1;
    const int lr = lane & 15;
    const int kb = (lane >> 4) * 8;

    for (int k0 = 0; k0 < 1024; k0 += BK) {
        __syncthreads();
#pragma unroll
        for (int rr = 0; rr < 4; rr++) {
            const int row = rr * 32 + srow_t;
            float4 av = make_float4(0.f, 0.f, 0.f, 0.f);
            if (grow[rr] >= 0)
                av = *(const float4*)(x + (size_t)grow[rr] * 1024 + k0 + scol);
            ushort4 pa;
            pa.x = f2b(av.x); pa.y = f2b(av.y); pa.z = f2b(av.z); pa.w = f2b(av.w);
            *(ushort4*)&As[row][scol] = pa;

            float4 gv = *(const float4*)(Bgp + (size_t)row * 1024 + k0 + scol);
            ushort4 pg;
            pg.x = f2b(gv.x); pg.y = f2b(gv.y); pg.z = f2b(gv.z); pg.w = f2b(gv.w);
            *(ushort4*)&Bg[row][scol] = pg;

            float4 sv = *(const float4*)(Bsp + (size_t)row * 1024 + k0 + scol);
            ushort4 ps;
            ps.x = f2b(sv.x); ps.y = f2b(sv.y); ps.z = f2b(sv.z); ps.w = f2b(sv.w);
            *(ushort4*)&Bs[row][scol] = ps;
        }
        __syncthreads();

        short8 af[4], bgf[4], bsf[4];
#pragma unroll
        for (int m = 0; m < 4; m++)
            af[m] = *(const short8*)&As[wr * 64 + m * 16 + lr][kb];
#pragma unroll
        for (int n = 0; n < 4; n++) {
            bgf[n] = *(const short8*)&Bg[wc * 64 + n * 16 + lr][kb];
            bsf[n] = *(const short8*)&Bs[wc * 64 + n * 16 + lr][kb];
        }
#pragma unroll
        for (int m = 0; m < 4; m++)
#pragma unroll
            for (int n = 0; n < 4; n++) {
                accg[m][n] = __builtin_amdgcn_mfma_f32_16x16x32_bf16(
                    af[m], bgf[n], accg[m][n], 0, 0, 0);
                accs[m][n] = __builtin_amdgcn_mfma_f32_16x16x32_bf16(
                    af[m], bsf[n], accs[m][n], 0, 0, 0);
            }
    }

    // epilogue: C/D layout col=lane&15, row=(lane>>4)*4+j  [m89/m91]
    const int rowoff = (lane >> 4) * 4;
#pragma unroll
    for (int m = 0; m < 4; m++) {
        const int prow = rbase + wr * 64 + m * 16 + rowoff;
#pragma unroll
        for (int n = 0; n < 4; n++) {
            const int col = cbase + wc * 64 + n * 16 + lr;
            const float b1g = b1[(size_t)gate * 4096 + col];
            const float b1s = b1[(size_t)GATES * 4096 + col];
#pragma unroll
            for (int j = 0; j < 4; j++) {
                float vg = accg[m][n][j] + b1g;
                float vs = accs[m][n][j] + b1s;
                float sv = 0.9f * fmaxf(vg, 0.f) + fmaxf(vs, 0.f);
                s_out[(size_t)(prow + j) * 4096 + col] = f2b(sv);
            }
        }
    }
}

// ---------------------------------------------------------------------------
// Layer 2: h2 = relu(s_perm @ W2^T + b2)   [NP,4096]x[2048,4096] -> bf16
// grid = (2048/BN=16, NROWT=40)
// ---------------------------------------------------------------------------
__global__ __launch_bounds__(256, 2)
void l2_kernel(const unsigned short* __restrict__ s_in,
               const float* __restrict__ W2,
               const float* __restrict__ b2,
               unsigned short* __restrict__ h2)
{
    __shared__ __align__(16) unsigned short As[BM][LDSW];
    __shared__ __align__(16) unsigned short Bt[BN][LDSW];

    const int t = threadIdx.x;
    const int rbase = blockIdx.y * BM;
    const int cbase = blockIdx.x * BN;
    const int srow_t = t >> 3;
    const int scol   = (t & 7) * 4;

    f32x4 acc[4][4];
#pragma unroll
    for (int m = 0; m < 4; m++)
#pragma unroll
        for (int n = 0; n < 4; n++) acc[m][n] = (f32x4){0.f, 0.f, 0.f, 0.f};

    const int lane = t & 63;
    const int wid  = t >> 6;
    const int wr = wid >> 1, wc = wid & 1;
    const int lr = lane & 15;
    const int kb = (lane >> 4) * 8;

    for (int k0 = 0; k0 < 4096; k0 += BK) {
        __syncthreads();
#pragma unroll
        for (int rr = 0; rr < 4; rr++) {
            const int row = rr * 32 + srow_t;
            ushort4 av = *(const ushort4*)(s_in + (size_t)(rbase + row) * 4096 + k0 + scol);
            *(ushort4*)&As[row][scol] = av;
            float4 bv = *(const float4*)(W2 + (size_t)(cbase + row) * 4096 + k0 + scol);
            ushort4 pb;
            pb.x = f2b(bv.x); pb.y = f2b(bv.y); pb.z = f2b(bv.z); pb.w = f2b(bv.w);
            *(ushort4*)&Bt[row][scol] = pb;
        }
        __syncthreads();

        short8 af[4], bf[4];
#pragma unroll
        for (int m = 0; m < 4; m++)
            af[m] = *(const short8*)&As[wr * 64 + m * 16 + lr][kb];
#pragma unroll
        for (int n = 0; n < 4; n++)
            bf[n] = *(const short8*)&Bt[wc * 64 + n * 16 + lr][kb];
#pragma unroll
        for (int m = 0; m < 4; m++)
#pragma unroll
            for (int n = 0; n < 4; n++)
                acc[m][n] = __builtin_amdgcn_mfma_f32_16x16x32_bf16(
                    af[m], bf[n], acc[m][n], 0, 0, 0);
    }

    const int rowoff = (lane >> 4) * 4;
#pragma unroll
    for (int m = 0; m < 4; m++) {
        const int prow = rbase + wr * 64 + m * 16 + rowoff;
#pragma unroll
        for (int n = 0; n < 4; n++) {
            const int col = cbase + wc * 64 + n * 16 + lr;
            const float bb = b2[col];
#pragma unroll
            for (int j = 0; j < 4; j++) {
                float v = fmaxf(acc[m][n][j] + bb, 0.f);
                h2[(size_t)(prow + j) * 2048 + col] = f2b(v);
            }
        }
    }
}

// ---------------------------------------------------------------------------
// Layer 3: out[perm[r]] = h2 @ W3^T   [NP,2048]x[1024,2048] -> f32 scatter
// grid = (1024/BN=8, NROWT=40)
// ---------------------------------------------------------------------------
__global__ __launch_bounds__(256, 2)
void l3_kernel(const unsigned short* __restrict__ h2,
               const float* __restrict__ W3,
               const int* __restrict__ perm,
               float* __restrict__ out)
{
    __shared__ __align__(16) unsigned short As[BM][LDSW];
    __shared__ __align__(16) unsigned short Bt[BN][LDSW];

    const int t = threadIdx.x;
    const int rbase = blockIdx.y * BM;
    const int cbase = blockIdx.x * BN;
    const int srow_t = t >> 3;
    const int scol   = (t & 7) * 4;

    f32x4 acc[4][4];
#pragma unroll
    for (int m = 0; m < 4; m++)
#pragma unroll
        for (int n = 0; n < 4; n++) acc[m][n] = (f32x4){0.f, 0.f, 0.f, 0.f};

    const int lane = t & 63;
    const int wid  = t >> 6;
    const int wr = wid >> 1, wc = wid & 1;
    const int lr = lane & 15;
    const int kb = (lane >> 4) * 8;

    for (int k0 = 0; k0 < 2048; k0 += BK) {
        __syncthreads();
#pragma unroll
        for (int rr = 0; rr < 4; rr++) {
            const int row = rr * 32 + srow_t;
            ushort4 av = *(const ushort4*)(h2 + (size_t)(rbase + row) * 2048 + k0 + scol);
            *(ushort4*)&As[row][scol] = av;
            float4 bv = *(const float4*)(W3 + (size_t)(cbase + row) * 2048 + k0 + scol);
            ushort4 pb;
            pb.x = f2b(bv.x); pb.y = f2b(bv.y); pb.z = f2b(bv.z); pb.w = f2b(bv.w);
            *(ushort4*)&Bt[row][scol] = pb;
        }
        __syncthreads();

        short8 af[4], bf[4];
#pragma unroll
        for (int m = 0; m < 4; m++)
            af[m] = *(const short8*)&As[wr * 64 + m * 16 + lr][kb];
#pragma unroll
        for (int n = 0; n < 4; n++)
            bf[n] = *(const short8*)&Bt[wc * 64 + n * 16 + lr][kb];
#pragma unroll
        for (int m = 0; m < 4; m++)
#pragma unroll
            for (int n = 0; n < 4; n++)
                acc[m][n] = __builtin_amdgcn_mfma_f32_16x16x32_bf16(
                    af[m], bf[n], acc[m][n], 0, 0, 0);
    }

    const int rowoff = (lane >> 4) * 4;
#pragma unroll
    for (int m = 0; m < 4; m++) {
        const int prow = rbase + wr * 64 + m * 16 + rowoff;
#pragma unroll
        for (int n = 0; n < 4; n++) {
            const int col = cbase + wc * 64 + n * 16 + lr;
#pragma unroll
            for (int j = 0; j < 4; j++) {
                int orow = perm[prow + j];
                if (orow >= 0)
                    out[(size_t)orow * 1024 + col] = acc[m][n][j];
            }
        }
    }
}

// ---------------------------------------------------------------------------
extern "C" void kernel_launch(void* const* d_in, const int* in_sizes, int n_in,
                              void* d_out, int out_size, void* d_ws, size_t ws_size,
                              hipStream_t stream)
{
    const float* x   = (const float*)d_in[0];
    const int*   gid = (const int*)d_in[1];
    const float* W1  = (const float*)d_in[2];
    const float* b1  = (const float*)d_in[3];
    const float* W2  = (const float*)d_in[4];
    const float* b2  = (const float*)d_in[5];
    const float* W3  = (const float*)d_in[6];
    float* out = (float*)d_out;

    // workspace layout
    const size_t perm_off = 0;                         // NP ints
    const size_t tg_off   = 20480;                     // NROWT ints
    const size_t s_off    = 32768;                     // NP*4096 bf16
    const size_t h2_off   = s_off + (size_t)NP * 4096 * 2;  // NP*2048 bf16
    const size_t needed   = h2_off + (size_t)NP * 2048 * 2;
    if (ws_size < needed) return;   // loud failure rather than OOB

    char* ws = (char*)d_ws;
    int* perm = (int*)(ws + perm_off);
    int* tile_gate = (int*)(ws + tg_off);
    unsigned short* s_perm = (unsigned short*)(ws + s_off);
    unsigned short* h2 = (unsigned short*)(ws + h2_off);

    bucket_kernel<<<1, 256, 0, stream>>>(gid, perm, tile_gate);
    l1_kernel<<<dim3(32, NROWT), 256, 0, stream>>>(x, W1, b1, perm, tile_gate, s_perm);
    l2_kernel<<<dim3(16, NROWT), 256, 0, stream>>>(s_perm, W2, b2, h2);
    l3_kernel<<<dim3(8, NROWT), 256, 0, stream>>>(h2, W3, perm, out);
}

// Round 3
// 546.084 us; speedup vs baseline: 1.4607x; 1.4607x over previous
//
#include <hip/hip_runtime.h>
#include <cstdint>

// ---------------------------------------------------------------------------
// GatedMLP: out = relu(relu(x@W1^T+b1) gated-blocksum @ W2^T + b2) @ W3^T
// N=4096, IN=1024, D=2048, G=8, 2D=4096, OUT=1024
// Round 3: pre-cast fp32->bf16, global_load_lds(16B) staging (m97 ladder).
// Fallback to round-2 reg-staged path if ws_size too small for bf16 copies.
// ---------------------------------------------------------------------------

#define NP 5120       // padded row space: 4096 + 8*128 slack
#define NROWT 40      // NP / 128
#define NROWS 4096
#define GATES 8

typedef short short8 __attribute__((ext_vector_type(8)));
typedef unsigned short ushort8v __attribute__((ext_vector_type(8)));
typedef float f32x4 __attribute__((ext_vector_type(4)));

constexpr int BM = 128, BN = 128, BK = 32;
constexpr int LDSW_FB = 40;   // fallback: 32 + 8 bf16 pad

__device__ __forceinline__ unsigned short f2b(float f) {
    __bf16 h = (__bf16)f;
    return __builtin_bit_cast(unsigned short, h);
}

// async global->LDS, 16 bytes per lane. LDS dest must be wave-uniform base;
// HW writes lane i at base + i*16.
__device__ __forceinline__ void gload_lds16(const void* g, void* l) {
    __builtin_amdgcn_global_load_lds(
        (const __attribute__((address_space(1))) void*)g,
        (__attribute__((address_space(3))) void*)l, 16, 0, 0);
}

// ---------------------------------------------------------------------------
// Kernel 0: bucket rows by gate id into padded segments (+ zero-row init)
// ---------------------------------------------------------------------------
__global__ void bucket_kernel(const int* __restrict__ gid,
                              int* __restrict__ perm,
                              int* __restrict__ tile_gate,
                              unsigned short* __restrict__ zrow)  // 1024 bf16 or null
{
    __shared__ int cnt[GATES], pstart[GATES], cur[GATES];
    const int t = threadIdx.x;
    if (zrow) {
        ushort4 z; z.x = 0; z.y = 0; z.z = 0; z.w = 0;
        ((ushort4*)zrow)[t] = z;              // 256 threads x 4 = 1024 elems
    }
    if (t < GATES) cnt[t] = 0;
    __syncthreads();
    for (int i = t; i < NROWS; i += 256) atomicAdd(&cnt[gid[i]], 1);
    __syncthreads();
    if (t == 0) {
        int off = 0;
        for (int g = 0; g < GATES; g++) {
            pstart[g] = off;
            cur[g] = 0;
            off += (cnt[g] + 127) & ~127;
        }
    }
    __syncthreads();
    for (int i = t; i < NP; i += 256) perm[i] = -1;
    if (t < NROWT) {
        int r0 = t * 128;
        int tg = 0;
        for (int g = 0; g < GATES; g++) {
            int pc = (cnt[g] + 127) & ~127;
            if (r0 >= pstart[g] && r0 < pstart[g] + pc) tg = g;
        }
        tile_gate[t] = tg;
    }
    __syncthreads();
    for (int i = t; i < NROWS; i += 256) {
        int g = gid[i];
        int p = atomicAdd(&cur[g], 1);
        perm[pstart[g] + p] = i;
    }
}

// ---------------------------------------------------------------------------
// fp32 -> bf16 cast pass (memory-bound, 8 floats/thread/iter)
// ---------------------------------------------------------------------------
__global__ __launch_bounds__(256)
void cast_kernel(const float* __restrict__ src, unsigned short* __restrict__ dst,
                 int n8)
{
    int i = blockIdx.x * 256 + threadIdx.x;
    const int stride = gridDim.x * 256;
    for (; i < n8; i += stride) {
        const float4* s4 = (const float4*)(src + (size_t)i * 8);
        float4 a = s4[0], b = s4[1];
        ushort8v v;
        v[0] = f2b(a.x); v[1] = f2b(a.y); v[2] = f2b(a.z); v[3] = f2b(a.w);
        v[4] = f2b(b.x); v[5] = f2b(b.y); v[6] = f2b(b.z); v[7] = f2b(b.w);
        *(ushort8v*)(dst + (size_t)i * 8) = v;
    }
}

// ---------------------------------------------------------------------------
// FAST PATH: bf16 everywhere, global_load_lds staging, linear LDS tiles.
// Tile staging map (tile = [128 rows][32 k] bf16 = 8192 B):
//   thread t, load j in {0,1}: row = (t>>2)+j*64, kcol = (t&3)*8
//   LDS chunk base (wave-uniform) = (t>>6)*1024 + j*4096 bytes
// ---------------------------------------------------------------------------
__global__ __launch_bounds__(256, 2)
void l1_fast(const unsigned short* __restrict__ xbf,   // [4097][1024], row 4096 = zeros
             const unsigned short* __restrict__ W1bf,  // [36864][1024]
             const float* __restrict__ b1,
             const int* __restrict__ perm,
             const int* __restrict__ tile_gate,
             unsigned short* __restrict__ s_out)       // [NP][4096]
{
    __shared__ __align__(16) unsigned short As[BM][BK];
    __shared__ __align__(16) unsigned short Bg[BN][BK];
    __shared__ __align__(16) unsigned short Bs[BN][BK];

    const int t = threadIdx.x;
    const int rbase = blockIdx.y * BM;
    const int cbase = blockIdx.x * BN;
    const int gate = tile_gate[blockIdx.y];

    const int srow  = t >> 2;          // 0..63
    const int skcol = (t & 3) * 8;     // 0,8,16,24

    int g0 = perm[rbase + srow];      if (g0 < 0) g0 = NROWS;
    int g1 = perm[rbase + srow + 64]; if (g1 < 0) g1 = NROWS;

    const unsigned short* a0 = xbf + (size_t)g0 * 1024 + skcol;
    const unsigned short* a1 = xbf + (size_t)g1 * 1024 + skcol;
    const unsigned short* bg0 = W1bf + ((size_t)(gate * 4096 + cbase + srow)) * 1024 + skcol;
    const unsigned short* bg1 = bg0 + (size_t)64 * 1024;
    const unsigned short* bs0 = W1bf + ((size_t)(GATES * 4096 + cbase + srow)) * 1024 + skcol;
    const unsigned short* bs1 = bs0 + (size_t)64 * 1024;

    const int wchunk = (t >> 6) * 1024;   // byte offset of this wave's LDS chunk

    f32x4 accg[4][4], accs[4][4];
#pragma unroll
    for (int m = 0; m < 4; m++)
#pragma unroll
        for (int n = 0; n < 4; n++) {
            accg[m][n] = (f32x4){0.f, 0.f, 0.f, 0.f};
            accs[m][n] = (f32x4){0.f, 0.f, 0.f, 0.f};
        }

    const int lane = t & 63;
    const int wid  = t >> 6;
    const int wr = wid >> 1, wc = wid & 1;
    const int lr = lane & 15;
    const int kb = (lane >> 4) * 8;

    for (int k0 = 0; k0 < 1024; k0 += BK) {
        gload_lds16(a0 + k0,  (char*)As + wchunk);
        gload_lds16(a1 + k0,  (char*)As + wchunk + 4096);
        gload_lds16(bg0 + k0, (char*)Bg + wchunk);
        gload_lds16(bg1 + k0, (char*)Bg + wchunk + 4096);
        gload_lds16(bs0 + k0, (char*)Bs + wchunk);
        gload_lds16(bs1 + k0, (char*)Bs + wchunk + 4096);
        __syncthreads();   // compiler drains vmcnt(0) before barrier

        short8 af[4];
#pragma unroll
        for (int m = 0; m < 4; m++)
            af[m] = *(const short8*)&As[wr * 64 + m * 16 + lr][kb];
        {
            short8 bf[4];
#pragma unroll
            for (int n = 0; n < 4; n++)
                bf[n] = *(const short8*)&Bg[wc * 64 + n * 16 + lr][kb];
#pragma unroll
            for (int m = 0; m < 4; m++)
#pragma unroll
                for (int n = 0; n < 4; n++)
                    accg[m][n] = __builtin_amdgcn_mfma_f32_16x16x32_bf16(
                        af[m], bf[n], accg[m][n], 0, 0, 0);
        }
        {
            short8 bf[4];
#pragma unroll
            for (int n = 0; n < 4; n++)
                bf[n] = *(const short8*)&Bs[wc * 64 + n * 16 + lr][kb];
#pragma unroll
            for (int m = 0; m < 4; m++)
#pragma unroll
                for (int n = 0; n < 4; n++)
                    accs[m][n] = __builtin_amdgcn_mfma_f32_16x16x32_bf16(
                        af[m], bf[n], accs[m][n], 0, 0, 0);
        }
        __syncthreads();
    }

    const int rowoff = (lane >> 4) * 4;
#pragma unroll
    for (int m = 0; m < 4; m++) {
        const int prow = rbase + wr * 64 + m * 16 + rowoff;
#pragma unroll
        for (int n = 0; n < 4; n++) {
            const int col = cbase + wc * 64 + n * 16 + lr;
            const float b1g = b1[(size_t)gate * 4096 + col];
            const float b1s = b1[(size_t)GATES * 4096 + col];
#pragma unroll
            for (int j = 0; j < 4; j++) {
                float vg = accg[m][n][j] + b1g;
                float vs = accs[m][n][j] + b1s;
                float sv = 0.9f * fmaxf(vg, 0.f) + fmaxf(vs, 0.f);
                s_out[(size_t)(prow + j) * 4096 + col] = f2b(sv);
            }
        }
    }
}

__global__ __launch_bounds__(256, 2)
void l2_fast(const unsigned short* __restrict__ s_in,   // [NP][4096]
             const unsigned short* __restrict__ W2bf,   // [2048][4096]
             const float* __restrict__ b2,
             unsigned short* __restrict__ h2)           // [NP][2048]
{
    __shared__ __align__(16) unsigned short As[BM][BK];
    __shared__ __align__(16) unsigned short Bt[BN][BK];

    const int t = threadIdx.x;
    const int rbase = blockIdx.y * BM;
    const int cbase = blockIdx.x * BN;
    const int srow  = t >> 2;
    const int skcol = (t & 3) * 8;

    const unsigned short* a0 = s_in + (size_t)(rbase + srow) * 4096 + skcol;
    const unsigned short* a1 = a0 + (size_t)64 * 4096;
    const unsigned short* b0 = W2bf + (size_t)(cbase + srow) * 4096 + skcol;
    const unsigned short* b1p = b0 + (size_t)64 * 4096;

    const int wchunk = (t >> 6) * 1024;

    f32x4 acc[4][4];
#pragma unroll
    for (int m = 0; m < 4; m++)
#pragma unroll
        for (int n = 0; n < 4; n++) acc[m][n] = (f32x4){0.f, 0.f, 0.f, 0.f};

    const int lane = t & 63;
    const int wid  = t >> 6;
    const int wr = wid >> 1, wc = wid & 1;
    const int lr = lane & 15;
    const int kb = (lane >> 4) * 8;

    for (int k0 = 0; k0 < 4096; k0 += BK) {
        gload_lds16(a0 + k0,  (char*)As + wchunk);
        gload_lds16(a1 + k0,  (char*)As + wchunk + 4096);
        gload_lds16(b0 + k0,  (char*)Bt + wchunk);
        gload_lds16(b1p + k0, (char*)Bt + wchunk + 4096);
        __syncthreads();

        short8 af[4], bf[4];
#pragma unroll
        for (int m = 0; m < 4; m++)
            af[m] = *(const short8*)&As[wr * 64 + m * 16 + lr][kb];
#pragma unroll
        for (int n = 0; n < 4; n++)
            bf[n] = *(const short8*)&Bt[wc * 64 + n * 16 + lr][kb];
#pragma unroll
        for (int m = 0; m < 4; m++)
#pragma unroll
            for (int n = 0; n < 4; n++)
                acc[m][n] = __builtin_amdgcn_mfma_f32_16x16x32_bf16(
                    af[m], bf[n], acc[m][n], 0, 0, 0);
        __syncthreads();
    }

    const int rowoff = (lane >> 4) * 4;
#pragma unroll
    for (int m = 0; m < 4; m++) {
        const int prow = rbase + wr * 64 + m * 16 + rowoff;
#pragma unroll
        for (int n = 0; n < 4; n++) {
            const int col = cbase + wc * 64 + n * 16 + lr;
            const float bb = b2[col];
#pragma unroll
            for (int j = 0; j < 4; j++) {
                float v = fmaxf(acc[m][n][j] + bb, 0.f);
                h2[(size_t)(prow + j) * 2048 + col] = f2b(v);
            }
        }
    }
}

__global__ __launch_bounds__(256, 2)
void l3_fast(const unsigned short* __restrict__ h2,     // [NP][2048]
             const unsigned short* __restrict__ W3bf,   // [1024][2048]
             const int* __restrict__ perm,
             float* __restrict__ out)                   // [4096][1024]
{
    __shared__ __align__(16) unsigned short As[BM][BK];
    __shared__ __align__(16) unsigned short Bt[BN][BK];

    const int t = threadIdx.x;
    const int rbase = blockIdx.y * BM;
    const int cbase = blockIdx.x * BN;
    const int srow  = t >> 2;
    const int skcol = (t & 3) * 8;

    const unsigned short* a0 = h2 + (size_t)(rbase + srow) * 2048 + skcol;
    const unsigned short* a1 = a0 + (size_t)64 * 2048;
    const unsigned short* b0 = W3bf + (size_t)(cbase + srow) * 2048 + skcol;
    const unsigned short* b1p = b0 + (size_t)64 * 2048;

    const int wchunk = (t >> 6) * 1024;

    f32x4 acc[4][4];
#pragma unroll
    for (int m = 0; m < 4; m++)
#pragma unroll
        for (int n = 0; n < 4; n++) acc[m][n] = (f32x4){0.f, 0.f, 0.f, 0.f};

    const int lane = t & 63;
    const int wid  = t >> 6;
    const int wr = wid >> 1, wc = wid & 1;
    const int lr = lane & 15;
    const int kb = (lane >> 4) * 8;

    for (int k0 = 0; k0 < 2048; k0 += BK) {
        gload_lds16(a0 + k0,  (char*)As + wchunk);
        gload_lds16(a1 + k0,  (char*)As + wchunk + 4096);
        gload_lds16(b0 + k0,  (char*)Bt + wchunk);
        gload_lds16(b1p + k0, (char*)Bt + wchunk + 4096);
        __syncthreads();

        short8 af[4], bf[4];
#pragma unroll
        for (int m = 0; m < 4; m++)
            af[m] = *(const short8*)&As[wr * 64 + m * 16 + lr][kb];
#pragma unroll
        for (int n = 0; n < 4; n++)
            bf[n] = *(const short8*)&Bt[wc * 64 + n * 16 + lr][kb];
#pragma unroll
        for (int m = 0; m < 4; m++)
#pragma unroll
            for (int n = 0; n < 4; n++)
                acc[m][n] = __builtin_amdgcn_mfma_f32_16x16x32_bf16(
                    af[m], bf[n], acc[m][n], 0, 0, 0);
        __syncthreads();
    }

    const int rowoff = (lane >> 4) * 4;
#pragma unroll
    for (int m = 0; m < 4; m++) {
        const int prow = rbase + wr * 64 + m * 16 + rowoff;
#pragma unroll
        for (int n = 0; n < 4; n++) {
            const int col = cbase + wc * 64 + n * 16 + lr;
#pragma unroll
            for (int j = 0; j < 4; j++) {
                int orow = perm[prow + j];
                if (orow >= 0)
                    out[(size_t)orow * 1024 + col] = acc[m][n][j];
            }
        }
    }
}

// ---------------------------------------------------------------------------
// FALLBACK PATH (round-2 verified kernels, fp32 reg-staged)
// ---------------------------------------------------------------------------
__global__ __launch_bounds__(256, 2)
void l1_fb(const float* __restrict__ x, const float* __restrict__ W1,
           const float* __restrict__ b1, const int* __restrict__ perm,
           const int* __restrict__ tile_gate, unsigned short* __restrict__ s_out)
{
    __shared__ __align__(16) unsigned short As[BM][LDSW_FB];
    __shared__ __align__(16) unsigned short Bg[BN][LDSW_FB];
    __shared__ __align__(16) unsigned short Bs[BN][LDSW_FB];

    const int t = threadIdx.x;
    const int rbase = blockIdx.y * BM;
    const int cbase = blockIdx.x * BN;
    const int gate = tile_gate[blockIdx.y];
    const int srow_t = t >> 3;
    const int scol   = (t & 7) * 4;

    int grow[4];
#pragma unroll
    for (int rr = 0; rr < 4; rr++) grow[rr] = perm[rbase + rr * 32 + srow_t];

    const float* Bgp = W1 + ((size_t)gate * 4096 + cbase) * 1024;
    const float* Bsp = W1 + ((size_t)GATES * 4096 + cbase) * 1024;

    f32x4 accg[4][4], accs[4][4];
#pragma unroll
    for (int m = 0; m < 4; m++)
#pragma unroll
        for (int n = 0; n < 4; n++) {
            accg[m][n] = (f32x4){0.f, 0.f, 0.f, 0.f};
            accs[m][n] = (f32x4){0.f, 0.f, 0.f, 0.f};
        }

    const int lane = t & 63;
    const int wid  = t >> 6;
    const int wr = wid >> 1, wc = wid & 1;
    const int lr = lane & 15;
    const int kb = (lane >> 4) * 8;

    for (int k0 = 0; k0 < 1024; k0 += BK) {
        __syncthreads();
#pragma unroll
        for (int rr = 0; rr < 4; rr++) {
            const int row = rr * 32 + srow_t;
            float4 av = make_float4(0.f, 0.f, 0.f, 0.f);
            if (grow[rr] >= 0)
                av = *(const float4*)(x + (size_t)grow[rr] * 1024 + k0 + scol);
            ushort4 pa;
            pa.x = f2b(av.x); pa.y = f2b(av.y); pa.z = f2b(av.z); pa.w = f2b(av.w);
            *(ushort4*)&As[row][scol] = pa;

            float4 gv = *(const float4*)(Bgp + (size_t)row * 1024 + k0 + scol);
            ushort4 pg;
            pg.x = f2b(gv.x); pg.y = f2b(gv.y); pg.z = f2b(gv.z); pg.w = f2b(gv.w);
            *(ushort4*)&Bg[row][scol] = pg;

            float4 sv = *(const float4*)(Bsp + (size_t)row * 1024 + k0 + scol);
            ushort4 ps;
            ps.x = f2b(sv.x); ps.y = f2b(sv.y); ps.z = f2b(sv.z); ps.w = f2b(sv.w);
            *(ushort4*)&Bs[row][scol] = ps;
        }
        __syncthreads();

        short8 af[4], bgf[4], bsf[4];
#pragma unroll
        for (int m = 0; m < 4; m++)
            af[m] = *(const short8*)&As[wr * 64 + m * 16 + lr][kb];
#pragma unroll
        for (int n = 0; n < 4; n++) {
            bgf[n] = *(const short8*)&Bg[wc * 64 + n * 16 + lr][kb];
            bsf[n] = *(const short8*)&Bs[wc * 64 + n * 16 + lr][kb];
        }
#pragma unroll
        for (int m = 0; m < 4; m++)
#pragma unroll
            for (int n = 0; n < 4; n++) {
                accg[m][n] = __builtin_amdgcn_mfma_f32_16x16x32_bf16(
                    af[m], bgf[n], accg[m][n], 0, 0, 0);
                accs[m][n] = __builtin_amdgcn_mfma_f32_16x16x32_bf16(
                    af[m], bsf[n], accs[m][n], 0, 0, 0);
            }
    }

    const int rowoff = (lane >> 4) * 4;
#pragma unroll
    for (int m = 0; m < 4; m++) {
        const int prow = rbase + wr * 64 + m * 16 + rowoff;
#pragma unroll
        for (int n = 0; n < 4; n++) {
            const int col = cbase + wc * 64 + n * 16 + lr;
            const float b1g = b1[(size_t)gate * 4096 + col];
            const float b1s = b1[(size_t)GATES * 4096 + col];
#pragma unroll
            for (int j = 0; j < 4; j++) {
                float vg = accg[m][n][j] + b1g;
                float vs = accs[m][n][j] + b1s;
                float sv = 0.9f * fmaxf(vg, 0.f) + fmaxf(vs, 0.f);
                s_out[(size_t)(prow + j) * 4096 + col] = f2b(sv);
            }
        }
    }
}

__global__ __launch_bounds__(256, 2)
void l2_fb(const unsigned short* __restrict__ s_in, const float* __restrict__ W2,
           const float* __restrict__ b2, unsigned short* __restrict__ h2)
{
    __shared__ __align__(16) unsigned short As[BM][LDSW_FB];
    __shared__ __align__(16) unsigned short Bt[BN][LDSW_FB];

    const int t = threadIdx.x;
    const int rbase = blockIdx.y * BM;
    const int cbase = blockIdx.x * BN;
    const int srow_t = t >> 3;
    const int scol   = (t & 7) * 4;

    f32x4 acc[4][4];
#pragma unroll
    for (int m = 0; m < 4; m++)
#pragma unroll
        for (int n = 0; n < 4; n++) acc[m][n] = (f32x4){0.f, 0.f, 0.f, 0.f};

    const int lane = t & 63;
    const int wid  = t >> 6;
    const int wr = wid >> 1, wc = wid & 1;
    const int lr = lane & 15;
    const int kb = (lane >> 4) * 8;

    for (int k0 = 0; k0 < 4096; k0 += BK) {
        __syncthreads();
#pragma unroll
        for (int rr = 0; rr < 4; rr++) {
            const int row = rr * 32 + srow_t;
            ushort4 av = *(const ushort4*)(s_in + (size_t)(rbase + row) * 4096 + k0 + scol);
            *(ushort4*)&As[row][scol] = av;
            float4 bv = *(const float4*)(W2 + (size_t)(cbase + row) * 4096 + k0 + scol);
            ushort4 pb;
            pb.x = f2b(bv.x); pb.y = f2b(bv.y); pb.z = f2b(bv.z); pb.w = f2b(bv.w);
            *(ushort4*)&Bt[row][scol] = pb;
        }
        __syncthreads();

        short8 af[4], bf[4];
#pragma unroll
        for (int m = 0; m < 4; m++)
            af[m] = *(const short8*)&As[wr * 64 + m * 16 + lr][kb];
#pragma unroll
        for (int n = 0; n < 4; n++)
            bf[n] = *(const short8*)&Bt[wc * 64 + n * 16 + lr][kb];
#pragma unroll
        for (int m = 0; m < 4; m++)
#pragma unroll
            for (int n = 0; n < 4; n++)
                acc[m][n] = __builtin_amdgcn_mfma_f32_16x16x32_bf16(
                    af[m], bf[n], acc[m][n], 0, 0, 0);
    }

    const int rowoff = (lane >> 4) * 4;
#pragma unroll
    for (int m = 0; m < 4; m++) {
        const int prow = rbase + wr * 64 + m * 16 + rowoff;
#pragma unroll
        for (int n = 0; n < 4; n++) {
            const int col = cbase + wc * 64 + n * 16 + lr;
            const float bb = b2[col];
#pragma unroll
            for (int j = 0; j < 4; j++) {
                float v = fmaxf(acc[m][n][j] + bb, 0.f);
                h2[(size_t)(prow + j) * 2048 + col] = f2b(v);
            }
        }
    }
}

__global__ __launch_bounds__(256, 2)
void l3_fb(const unsigned short* __restrict__ h2, const float* __restrict__ W3,
           const int* __restrict__ perm, float* __restrict__ out)
{
    __shared__ __align__(16) unsigned short As[BM][LDSW_FB];
    __shared__ __align__(16) unsigned short Bt[BN][LDSW_FB];

    const int t = threadIdx.x;
    const int rbase = blockIdx.y * BM;
    const int cbase = blockIdx.x * BN;
    const int srow_t = t >> 3;
    const int scol   = (t & 7) * 4;

    f32x4 acc[4][4];
#pragma unroll
    for (int m = 0; m < 4; m++)
#pragma unroll
        for (int n = 0; n < 4; n++) acc[m][n] = (f32x4){0.f, 0.f, 0.f, 0.f};

    const int lane = t & 63;
    const int wid  = t >> 6;
    const int wr = wid >> 1, wc = wid & 1;
    const int lr = lane & 15;
    const int kb = (lane >> 4) * 8;

    for (int k0 = 0; k0 < 2048; k0 += BK) {
        __syncthreads();
#pragma unroll
        for (int rr = 0; rr < 4; rr++) {
            const int row = rr * 32 + srow_t;
            ushort4 av = *(const ushort4*)(h2 + (size_t)(rbase + row) * 2048 + k0 + scol);
            *(ushort4*)&As[row][scol] = av;
            float4 bv = *(const float4*)(W3 + (size_t)(cbase + row) * 2048 + k0 + scol);
            ushort4 pb;
            pb.x = f2b(bv.x); pb.y = f2b(bv.y); pb.z = f2b(bv.z); pb.w = f2b(bv.w);
            *(ushort4*)&Bt[row][scol] = pb;
        }
        __syncthreads();

        short8 af[4], bf[4];
#pragma unroll
        for (int m = 0; m < 4; m++)
            af[m] = *(const short8*)&As[wr * 64 + m * 16 + lr][kb];
#pragma unroll
        for (int n = 0; n < 4; n++)
            bf[n] = *(const short8*)&Bt[wc * 64 + n * 16 + lr][kb];
#pragma unroll
        for (int m = 0; m < 4; m++)
#pragma unroll
            for (int n = 0; n < 4; n++)
                acc[m][n] = __builtin_amdgcn_mfma_f32_16x16x32_bf16(
                    af[m], bf[n], acc[m][n], 0, 0, 0);
    }

    const int rowoff = (lane >> 4) * 4;
#pragma unroll
    for (int m = 0; m < 4; m++) {
        const int prow = rbase + wr * 64 + m * 16 + rowoff;
#pragma unroll
        for (int n = 0; n < 4; n++) {
            const int col = cbase + wc * 64 + n * 16 + lr;
#pragma unroll
            for (int j = 0; j < 4; j++) {
                int orow = perm[prow + j];
                if (orow >= 0)
                    out[(size_t)orow * 1024 + col] = acc[m][n][j];
            }
        }
    }
}

// ---------------------------------------------------------------------------
extern "C" void kernel_launch(void* const* d_in, const int* in_sizes, int n_in,
                              void* d_out, int out_size, void* d_ws, size_t ws_size,
                              hipStream_t stream)
{
    const float* x   = (const float*)d_in[0];
    const int*   gid = (const int*)d_in[1];
    const float* W1  = (const float*)d_in[2];
    const float* b1  = (const float*)d_in[3];
    const float* W2  = (const float*)d_in[4];
    const float* b2  = (const float*)d_in[5];
    const float* W3  = (const float*)d_in[6];
    float* out = (float*)d_out;
    char* ws = (char*)d_ws;

    auto alignup = [](size_t v) { return (v + 255) & ~(size_t)255; };

    // ---- big (fast-path) layout ----
    size_t off = 0;
    const size_t perm_off = off; off = alignup(off + (size_t)NP * 4);
    const size_t tg_off   = off; off = alignup(off + (size_t)NROWT * 4);
    const size_t xbf_off  = off; off = alignup(off + (size_t)4097 * 1024 * 2);
    const size_t w1_off   = off; off = alignup(off + (size_t)36864 * 1024 * 2);
    const size_t w2_off   = off; off = alignup(off + (size_t)2048 * 4096 * 2);
    const size_t w3_off   = off; off = alignup(off + (size_t)1024 * 2048 * 2);
    const size_t sB_off   = off; off = alignup(off + (size_t)NP * 4096 * 2);
    const size_t h2B_off  = off; off = alignup(off + (size_t)NP * 2048 * 2);
    const size_t need_big = off;

    // ---- small (fallback) layout (round-2 verified) ----
    const size_t sS_off   = 32768;
    const size_t h2S_off  = sS_off + (size_t)NP * 4096 * 2;
    const size_t need_sm  = h2S_off + (size_t)NP * 2048 * 2;

    int* perm = (int*)(ws + perm_off);
    int* tile_gate = (int*)(ws + tg_off);

    if (ws_size >= need_big) {
        unsigned short* xbf  = (unsigned short*)(ws + xbf_off);
        unsigned short* w1bf = (unsigned short*)(ws + w1_off);
        unsigned short* w2bf = (unsigned short*)(ws + w2_off);
        unsigned short* w3bf = (unsigned short*)(ws + w3_off);
        unsigned short* s_perm = (unsigned short*)(ws + sB_off);
        unsigned short* h2 = (unsigned short*)(ws + h2B_off);
        unsigned short* zrow = xbf + (size_t)NROWS * 1024;   // row 4096

        bucket_kernel<<<1, 256, 0, stream>>>(gid, perm, tile_gate, zrow);
        cast_kernel<<<2048, 256, 0, stream>>>(x,  xbf,  (NROWS * 1024) / 8);
        cast_kernel<<<2048, 256, 0, stream>>>(W1, w1bf, (36864 * 1024) / 8);
        cast_kernel<<<2048, 256, 0, stream>>>(W2, w2bf, (2048 * 4096) / 8);
        cast_kernel<<<1024, 256, 0, stream>>>(W3, w3bf, (1024 * 2048) / 8);
        l1_fast<<<dim3(32, NROWT), 256, 0, stream>>>(xbf, w1bf, b1, perm, tile_gate, s_perm);
        l2_fast<<<dim3(16, NROWT), 256, 0, stream>>>(s_perm, w2bf, b2, h2);
        l3_fast<<<dim3(8, NROWT), 256, 0, stream>>>(h2, w3bf, perm, out);
    } else if (ws_size >= need_sm) {
        // fallback: round-2 path, perm/tg at same offsets (0 / 20480)
        unsigned short* s_perm = (unsigned short*)(ws + sS_off);
        unsigned short* h2 = (unsigned short*)(ws + h2S_off);

        bucket_kernel<<<1, 256, 0, stream>>>(gid, perm, tile_gate, (unsigned short*)nullptr);
        l1_fb<<<dim3(32, NROWT), 256, 0, stream>>>(x, W1, b1, perm, tile_gate, s_perm);
        l2_fb<<<dim3(16, NROWT), 256, 0, stream>>>(s_perm, W2, b2, h2);
        l3_fb<<<dim3(8, NROWT), 256, 0, stream>>>(h2, W3, perm, out);
    }
    // else: ws too small even for fallback -> loud failure
}

// Round 6
// 542.519 us; speedup vs baseline: 1.4703x; 1.0066x over previous
//
#include <hip/hip_runtime.h>
#include <cstdint>

// ---------------------------------------------------------------------------
// GatedMLP: out = relu(relu(x@W1^T+b1) gated-blocksum @ W2^T + b2) @ W3^T
// N=4096, IN=1024, D=2048, G=8, 2D=4096, OUT=1024
// Round 6: revert launch_bounds to (256,2) — the (256,4) cap forced
// accumulator spills (128 acc regs + 96 arch > 128 budget) => 2.4x slowdown
// and replay divergence.  KEEP the 2-way LDS slot swizzle (verified correct
// on first call in round 5).
// ---------------------------------------------------------------------------

#define NP 5120       // padded row space: 4096 + 8*128 slack
#define NROWT 40      // NP / 128
#define NROWS 4096
#define GATES 8

typedef short short8 __attribute__((ext_vector_type(8)));
typedef unsigned short ushort8v __attribute__((ext_vector_type(8)));
typedef float f32x4 __attribute__((ext_vector_type(4)));

constexpr int BM = 128, BN = 128, BK = 32;
constexpr int LDSW_FB = 40;   // fallback: 32 + 8 bf16 pad

__device__ __forceinline__ unsigned short f2b(float f) {
    __bf16 h = (__bf16)f;
    return __builtin_bit_cast(unsigned short, h);
}

// async global->LDS, 16 bytes per lane. LDS dest is wave-uniform base;
// HW writes lane i at base + i*16 (linear).
__device__ __forceinline__ void gload_lds16(const void* g, void* l) {
    __builtin_amdgcn_global_load_lds(
        (const __attribute__((address_space(1))) void*)g,
        (__attribute__((address_space(3))) void*)l, 16, 0, 0);
}

// Swizzle: tile row r (64B = four 16B slots), logical slot q stored at
// q ^ ((r>>1)&3).  Involution; staging pre-applies it to the global source,
// reads apply it to the LDS address.  Banks: 16 rows x same q -> 8 quads x2.
// Staging thread t covers (row = t>>2 [+64], slot = t&3):
//   swizzled source slot = (t&3) ^ ((t>>3)&3)
// Read lane: logical q = lane>>4, row = ...+lr (lr=lane&15):
//   slot = (lane>>4) ^ ((lr>>1)&3)

// ---------------------------------------------------------------------------
// Kernel 0: bucket rows by gate id into padded segments (+ zero-row init)
// ---------------------------------------------------------------------------
__global__ void bucket_kernel(const int* __restrict__ gid,
                              int* __restrict__ perm,
                              int* __restrict__ tile_gate,
                              unsigned short* __restrict__ zrow)  // 1024 bf16 or null
{
    __shared__ int cnt[GATES], pstart[GATES], cur[GATES];
    const int t = threadIdx.x;
    if (zrow) {
        ushort4 z; z.x = 0; z.y = 0; z.z = 0; z.w = 0;
        ((ushort4*)zrow)[t] = z;              // 256 threads x 4 = 1024 elems
    }
    if (t < GATES) cnt[t] = 0;
    __syncthreads();
    for (int i = t; i < NROWS; i += 256) atomicAdd(&cnt[gid[i]], 1);
    __syncthreads();
    if (t == 0) {
        int off = 0;
        for (int g = 0; g < GATES; g++) {
            pstart[g] = off;
            cur[g] = 0;
            off += (cnt[g] + 127) & ~127;
        }
    }
    __syncthreads();
    for (int i = t; i < NP; i += 256) perm[i] = -1;
    if (t < NROWT) {
        int r0 = t * 128;
        int tg = 0;
        for (int g = 0; g < GATES; g++) {
            int pc = (cnt[g] + 127) & ~127;
            if (r0 >= pstart[g] && r0 < pstart[g] + pc) tg = g;
        }
        tile_gate[t] = tg;
    }
    __syncthreads();
    for (int i = t; i < NROWS; i += 256) {
        int g = gid[i];
        int p = atomicAdd(&cur[g], 1);
        perm[pstart[g] + p] = i;
    }
}

// ---------------------------------------------------------------------------
// fp32 -> bf16 cast pass (memory-bound, 8 floats/thread/iter)
// ---------------------------------------------------------------------------
__global__ __launch_bounds__(256)
void cast_kernel(const float* __restrict__ src, unsigned short* __restrict__ dst,
                 int n8)
{
    int i = blockIdx.x * 256 + threadIdx.x;
    const int stride = gridDim.x * 256;
    for (; i < n8; i += stride) {
        const float4* s4 = (const float4*)(src + (size_t)i * 8);
        float4 a = s4[0], b = s4[1];
        ushort8v v;
        v[0] = f2b(a.x); v[1] = f2b(a.y); v[2] = f2b(a.z); v[3] = f2b(a.w);
        v[4] = f2b(b.x); v[5] = f2b(b.y); v[6] = f2b(b.z); v[7] = f2b(b.w);
        *(ushort8v*)(dst + (size_t)i * 8) = v;
    }
}

// ---------------------------------------------------------------------------
// FAST PATH GEMMs
// ---------------------------------------------------------------------------
__global__ __launch_bounds__(256, 2)
void l1_fast(const unsigned short* __restrict__ xbf,   // [4097][1024], row 4096 = zeros
             const unsigned short* __restrict__ W1bf,  // [36864][1024]
             const float* __restrict__ b1,
             const int* __restrict__ perm,
             const int* __restrict__ tile_gate,
             unsigned short* __restrict__ s_out)       // [NP][4096]
{
    __shared__ __align__(16) unsigned short As[BM][BK];
    __shared__ __align__(16) unsigned short Bg[BN][BK];
    __shared__ __align__(16) unsigned short Bs[BN][BK];

    const int t = threadIdx.x;
    const int rbase = blockIdx.y * BM;
    const int cbase = blockIdx.x * BN;
    const int gate = tile_gate[blockIdx.y];

    const int srow  = t >> 2;                          // 0..63
    const int skcol = ((t & 3) ^ ((t >> 3) & 3)) * 8;  // swizzled source slot

    int g0 = perm[rbase + srow];      if (g0 < 0) g0 = NROWS;
    int g1 = perm[rbase + srow + 64]; if (g1 < 0) g1 = NROWS;

    const unsigned short* a0 = xbf + (size_t)g0 * 1024 + skcol;
    const unsigned short* a1 = xbf + (size_t)g1 * 1024 + skcol;
    const unsigned short* bg0 = W1bf + ((size_t)(gate * 4096 + cbase + srow)) * 1024 + skcol;
    const unsigned short* bg1 = bg0 + (size_t)64 * 1024;
    const unsigned short* bs0 = W1bf + ((size_t)(GATES * 4096 + cbase + srow)) * 1024 + skcol;
    const unsigned short* bs1 = bs0 + (size_t)64 * 1024;

    const int wchunk = (t >> 6) * 1024;   // byte offset of this wave's LDS chunk

    f32x4 accg[4][4], accs[4][4];
#pragma unroll
    for (int m = 0; m < 4; m++)
#pragma unroll
        for (int n = 0; n < 4; n++) {
            accg[m][n] = (f32x4){0.f, 0.f, 0.f, 0.f};
            accs[m][n] = (f32x4){0.f, 0.f, 0.f, 0.f};
        }

    const int lane = t & 63;
    const int wid  = t >> 6;
    const int wr = wid >> 1, wc = wid & 1;
    const int lr = lane & 15;
    const int kb = (((lane >> 4) ^ ((lr >> 1) & 3))) * 8;  // swizzled read slot

    for (int k0 = 0; k0 < 1024; k0 += BK) {
        gload_lds16(a0 + k0,  (char*)As + wchunk);
        gload_lds16(a1 + k0,  (char*)As + wchunk + 4096);
        gload_lds16(bg0 + k0, (char*)Bg + wchunk);
        gload_lds16(bg1 + k0, (char*)Bg + wchunk + 4096);
        gload_lds16(bs0 + k0, (char*)Bs + wchunk);
        gload_lds16(bs1 + k0, (char*)Bs + wchunk + 4096);
        __syncthreads();   // compiler drains vmcnt(0) before barrier

        short8 af[4];
#pragma unroll
        for (int m = 0; m < 4; m++)
            af[m] = *(const short8*)&As[wr * 64 + m * 16 + lr][kb];
        {
            short8 bf[4];
#pragma unroll
            for (int n = 0; n < 4; n++)
                bf[n] = *(const short8*)&Bg[wc * 64 + n * 16 + lr][kb];
#pragma unroll
            for (int m = 0; m < 4; m++)
#pragma unroll
                for (int n = 0; n < 4; n++)
                    accg[m][n] = __builtin_amdgcn_mfma_f32_16x16x32_bf16(
                        af[m], bf[n], accg[m][n], 0, 0, 0);
        }
        {
            short8 bf[4];
#pragma unroll
            for (int n = 0; n < 4; n++)
                bf[n] = *(const short8*)&Bs[wc * 64 + n * 16 + lr][kb];
#pragma unroll
            for (int m = 0; m < 4; m++)
#pragma unroll
                for (int n = 0; n < 4; n++)
                    accs[m][n] = __builtin_amdgcn_mfma_f32_16x16x32_bf16(
                        af[m], bf[n], accs[m][n], 0, 0, 0);
        }
        __syncthreads();
    }

    const int rowoff = (lane >> 4) * 4;
#pragma unroll
    for (int m = 0; m < 4; m++) {
        const int prow = rbase + wr * 64 + m * 16 + rowoff;
#pragma unroll
        for (int n = 0; n < 4; n++) {
            const int col = cbase + wc * 64 + n * 16 + lr;
            const float b1g = b1[(size_t)gate * 4096 + col];
            const float b1s = b1[(size_t)GATES * 4096 + col];
#pragma unroll
            for (int j = 0; j < 4; j++) {
                float vg = accg[m][n][j] + b1g;
                float vs = accs[m][n][j] + b1s;
                float sv = 0.9f * fmaxf(vg, 0.f) + fmaxf(vs, 0.f);
                s_out[(size_t)(prow + j) * 4096 + col] = f2b(sv);
            }
        }
    }
}

__global__ __launch_bounds__(256, 2)
void l2_fast(const unsigned short* __restrict__ s_in,   // [NP][4096]
             const unsigned short* __restrict__ W2bf,   // [2048][4096]
             const float* __restrict__ b2,
             unsigned short* __restrict__ h2)           // [NP][2048]
{
    __shared__ __align__(16) unsigned short As[BM][BK];
    __shared__ __align__(16) unsigned short Bt[BN][BK];

    const int t = threadIdx.x;
    const int rbase = blockIdx.y * BM;
    const int cbase = blockIdx.x * BN;
    const int srow  = t >> 2;
    const int skcol = ((t & 3) ^ ((t >> 3) & 3)) * 8;

    const unsigned short* a0 = s_in + (size_t)(rbase + srow) * 4096 + skcol;
    const unsigned short* a1 = a0 + (size_t)64 * 4096;
    const unsigned short* b0 = W2bf + (size_t)(cbase + srow) * 4096 + skcol;
    const unsigned short* b1p = b0 + (size_t)64 * 4096;

    const int wchunk = (t >> 6) * 1024;

    f32x4 acc[4][4];
#pragma unroll
    for (int m = 0; m < 4; m++)
#pragma unroll
        for (int n = 0; n < 4; n++) acc[m][n] = (f32x4){0.f, 0.f, 0.f, 0.f};

    const int lane = t & 63;
    const int wid  = t >> 6;
    const int wr = wid >> 1, wc = wid & 1;
    const int lr = lane & 15;
    const int kb = (((lane >> 4) ^ ((lr >> 1) & 3))) * 8;

    for (int k0 = 0; k0 < 4096; k0 += BK) {
        gload_lds16(a0 + k0,  (char*)As + wchunk);
        gload_lds16(a1 + k0,  (char*)As + wchunk + 4096);
        gload_lds16(b0 + k0,  (char*)Bt + wchunk);
        gload_lds16(b1p + k0, (char*)Bt + wchunk + 4096);
        __syncthreads();

        short8 af[4], bf[4];
#pragma unroll
        for (int m = 0; m < 4; m++)
            af[m] = *(const short8*)&As[wr * 64 + m * 16 + lr][kb];
#pragma unroll
        for (int n = 0; n < 4; n++)
            bf[n] = *(const short8*)&Bt[wc * 64 + n * 16 + lr][kb];
#pragma unroll
        for (int m = 0; m < 4; m++)
#pragma unroll
            for (int n = 0; n < 4; n++)
                acc[m][n] = __builtin_amdgcn_mfma_f32_16x16x32_bf16(
                    af[m], bf[n], acc[m][n], 0, 0, 0);
        __syncthreads();
    }

    const int rowoff = (lane >> 4) * 4;
#pragma unroll
    for (int m = 0; m < 4; m++) {
        const int prow = rbase + wr * 64 + m * 16 + rowoff;
#pragma unroll
        for (int n = 0; n < 4; n++) {
            const int col = cbase + wc * 64 + n * 16 + lr;
            const float bb = b2[col];
#pragma unroll
            for (int j = 0; j < 4; j++) {
                float v = fmaxf(acc[m][n][j] + bb, 0.f);
                h2[(size_t)(prow + j) * 2048 + col] = f2b(v);
            }
        }
    }
}

__global__ __launch_bounds__(256, 2)
void l3_fast(const unsigned short* __restrict__ h2,     // [NP][2048]
             const unsigned short* __restrict__ W3bf,   // [1024][2048]
             const int* __restrict__ perm,
             float* __restrict__ out)                   // [4096][1024]
{
    __shared__ __align__(16) unsigned short As[BM][BK];
    __shared__ __align__(16) unsigned short Bt[BN][BK];

    const int t = threadIdx.x;
    const int rbase = blockIdx.y * BM;
    const int cbase = blockIdx.x * BN;
    const int srow  = t >> 2;
    const int skcol = ((t & 3) ^ ((t >> 3) & 3)) * 8;

    const unsigned short* a0 = h2 + (size_t)(rbase + srow) * 2048 + skcol;
    const unsigned short* a1 = a0 + (size_t)64 * 2048;
    const unsigned short* b0 = W3bf + (size_t)(cbase + srow) * 2048 + skcol;
    const unsigned short* b1p = b0 + (size_t)64 * 2048;

    const int wchunk = (t >> 6) * 1024;

    f32x4 acc[4][4];
#pragma unroll
    for (int m = 0; m < 4; m++)
#pragma unroll
        for (int n = 0; n < 4; n++) acc[m][n] = (f32x4){0.f, 0.f, 0.f, 0.f};

    const int lane = t & 63;
    const int wid  = t >> 6;
    const int wr = wid >> 1, wc = wid & 1;
    const int lr = lane & 15;
    const int kb = (((lane >> 4) ^ ((lr >> 1) & 3))) * 8;

    for (int k0 = 0; k0 < 2048; k0 += BK) {
        gload_lds16(a0 + k0,  (char*)As + wchunk);
        gload_lds16(a1 + k0,  (char*)As + wchunk + 4096);
        gload_lds16(b0 + k0,  (char*)Bt + wchunk);
        gload_lds16(b1p + k0, (char*)Bt + wchunk + 4096);
        __syncthreads();

        short8 af[4], bf[4];
#pragma unroll
        for (int m = 0; m < 4; m++)
            af[m] = *(const short8*)&As[wr * 64 + m * 16 + lr][kb];
#pragma unroll
        for (int n = 0; n < 4; n++)
            bf[n] = *(const short8*)&Bt[wc * 64 + n * 16 + lr][kb];
#pragma unroll
        for (int m = 0; m < 4; m++)
#pragma unroll
            for (int n = 0; n < 4; n++)
                acc[m][n] = __builtin_amdgcn_mfma_f32_16x16x32_bf16(
                    af[m], bf[n], acc[m][n], 0, 0, 0);
        __syncthreads();
    }

    const int rowoff = (lane >> 4) * 4;
#pragma unroll
    for (int m = 0; m < 4; m++) {
        const int prow = rbase + wr * 64 + m * 16 + rowoff;
#pragma unroll
        for (int n = 0; n < 4; n++) {
            const int col = cbase + wc * 64 + n * 16 + lr;
#pragma unroll
            for (int j = 0; j < 4; j++) {
                int orow = perm[prow + j];
                if (orow >= 0)
                    out[(size_t)orow * 1024 + col] = acc[m][n][j];
            }
        }
    }
}

// ---------------------------------------------------------------------------
// FALLBACK PATH (round-2 verified kernels, fp32 reg-staged)
// ---------------------------------------------------------------------------
__global__ __launch_bounds__(256, 2)
void l1_fb(const float* __restrict__ x, const float* __restrict__ W1,
           const float* __restrict__ b1, const int* __restrict__ perm,
           const int* __restrict__ tile_gate, unsigned short* __restrict__ s_out)
{
    __shared__ __align__(16) unsigned short As[BM][LDSW_FB];
    __shared__ __align__(16) unsigned short Bg[BN][LDSW_FB];
    __shared__ __align__(16) unsigned short Bs[BN][LDSW_FB];

    const int t = threadIdx.x;
    const int rbase = blockIdx.y * BM;
    const int cbase = blockIdx.x * BN;
    const int gate = tile_gate[blockIdx.y];
    const int srow_t = t >> 3;
    const int scol   = (t & 7) * 4;

    int grow[4];
#pragma unroll
    for (int rr = 0; rr < 4; rr++) grow[rr] = perm[rbase + rr * 32 + srow_t];

    const float* Bgp = W1 + ((size_t)gate * 4096 + cbase) * 1024;
    const float* Bsp = W1 + ((size_t)GATES * 4096 + cbase) * 1024;

    f32x4 accg[4][4], accs[4][4];
#pragma unroll
    for (int m = 0; m < 4; m++)
#pragma unroll
        for (int n = 0; n < 4; n++) {
            accg[m][n] = (f32x4){0.f, 0.f, 0.f, 0.f};
            accs[m][n] = (f32x4){0.f, 0.f, 0.f, 0.f};
        }

    const int lane = t & 63;
    const int wid  = t >> 6;
    const int wr = wid >> 1, wc = wid & 1;
    const int lr = lane & 15;
    const int kb = (lane >> 4) * 8;

    for (int k0 = 0; k0 < 1024; k0 += BK) {
        __syncthreads();
#pragma unroll
        for (int rr = 0; rr < 4; rr++) {
            const int row = rr * 32 + srow_t;
            float4 av = make_float4(0.f, 0.f, 0.f, 0.f);
            if (grow[rr] >= 0)
                av = *(const float4*)(x + (size_t)grow[rr] * 1024 + k0 + scol);
            ushort4 pa;
            pa.x = f2b(av.x); pa.y = f2b(av.y); pa.z = f2b(av.z); pa.w = f2b(av.w);
            *(ushort4*)&As[row][scol] = pa;

            float4 gv = *(const float4*)(Bgp + (size_t)row * 1024 + k0 + scol);
            ushort4 pg;
            pg.x = f2b(gv.x); pg.y = f2b(gv.y); pg.z = f2b(gv.z); pg.w = f2b(gv.w);
            *(ushort4*)&Bg[row][scol] = pg;

            float4 sv = *(const float4*)(Bsp + (size_t)row * 1024 + k0 + scol);
            ushort4 ps;
            ps.x = f2b(sv.x); ps.y = f2b(sv.y); ps.z = f2b(sv.z); ps.w = f2b(sv.w);
            *(ushort4*)&Bs[row][scol] = ps;
        }
        __syncthreads();

        short8 af[4], bgf[4], bsf[4];
#pragma unroll
        for (int m = 0; m < 4; m++)
            af[m] = *(const short8*)&As[wr * 64 + m * 16 + lr][kb];
#pragma unroll
        for (int n = 0; n < 4; n++) {
            bgf[n] = *(const short8*)&Bg[wc * 64 + n * 16 + lr][kb];
            bsf[n] = *(const short8*)&Bs[wc * 64 + n * 16 + lr][kb];
        }
#pragma unroll
        for (int m = 0; m < 4; m++)
#pragma unroll
            for (int n = 0; n < 4; n++) {
                accg[m][n] = __builtin_amdgcn_mfma_f32_16x16x32_bf16(
                    af[m], bgf[n], accg[m][n], 0, 0, 0);
                accs[m][n] = __builtin_amdgcn_mfma_f32_16x16x32_bf16(
                    af[m], bsf[n], accs[m][n], 0, 0, 0);
            }
    }

    const int rowoff = (lane >> 4) * 4;
#pragma unroll
    for (int m = 0; m < 4; m++) {
        const int prow = rbase + wr * 64 + m * 16 + rowoff;
#pragma unroll
        for (int n = 0; n < 4; n++) {
            const int col = cbase + wc * 64 + n * 16 + lr;
            const float b1g = b1[(size_t)gate * 4096 + col];
            const float b1s = b1[(size_t)GATES * 4096 + col];
#pragma unroll
            for (int j = 0; j < 4; j++) {
                float vg = accg[m][n][j] + b1g;
                float vs = accs[m][n][j] + b1s;
                float sv = 0.9f * fmaxf(vg, 0.f) + fmaxf(vs, 0.f);
                s_out[(size_t)(prow + j) * 4096 + col] = f2b(sv);
            }
        }
    }
}

__global__ __launch_bounds__(256, 2)
void l2_fb(const unsigned short* __restrict__ s_in, const float* __restrict__ W2,
           const float* __restrict__ b2, unsigned short* __restrict__ h2)
{
    __shared__ __align__(16) unsigned short As[BM][LDSW_FB];
    __shared__ __align__(16) unsigned short Bt[BN][LDSW_FB];

    const int t = threadIdx.x;
    const int rbase = blockIdx.y * BM;
    const int cbase = blockIdx.x * BN;
    const int srow_t = t >> 3;
    const int scol   = (t & 7) * 4;

    f32x4 acc[4][4];
#pragma unroll
    for (int m = 0; m < 4; m++)
#pragma unroll
        for (int n = 0; n < 4; n++) acc[m][n] = (f32x4){0.f, 0.f, 0.f, 0.f};

    const int lane = t & 63;
    const int wid  = t >> 6;
    const int wr = wid >> 1, wc = wid & 1;
    const int lr = lane & 15;
    const int kb = (lane >> 4) * 8;

    for (int k0 = 0; k0 < 4096; k0 += BK) {
        __syncthreads();
#pragma unroll
        for (int rr = 0; rr < 4; rr++) {
            const int row = rr * 32 + srow_t;
            ushort4 av = *(const ushort4*)(s_in + (size_t)(rbase + row) * 4096 + k0 + scol);
            *(ushort4*)&As[row][scol] = av;
            float4 bv = *(const float4*)(W2 + (size_t)(cbase + row) * 4096 + k0 + scol);
            ushort4 pb;
            pb.x = f2b(bv.x); pb.y = f2b(bv.y); pb.z = f2b(bv.z); pb.w = f2b(bv.w);
            *(ushort4*)&Bt[row][scol] = pb;
        }
        __syncthreads();

        short8 af[4], bf[4];
#pragma unroll
        for (int m = 0; m < 4; m++)
            af[m] = *(const short8*)&As[wr * 64 + m * 16 + lr][kb];
#pragma unroll
        for (int n = 0; n < 4; n++)
            bf[n] = *(const short8*)&Bt[wc * 64 + n * 16 + lr][kb];
#pragma unroll
        for (int m = 0; m < 4; m++)
#pragma unroll
            for (int n = 0; n < 4; n++)
                acc[m][n] = __builtin_amdgcn_mfma_f32_16x16x32_bf16(
                    af[m], bf[n], acc[m][n], 0, 0, 0);
    }

    const int rowoff = (lane >> 4) * 4;
#pragma unroll
    for (int m = 0; m < 4; m++) {
        const int prow = rbase + wr * 64 + m * 16 + rowoff;
#pragma unroll
        for (int n = 0; n < 4; n++) {
            const int col = cbase + wc * 64 + n * 16 + lr;
            const float bb = b2[col];
#pragma unroll
            for (int j = 0; j < 4; j++) {
                float v = fmaxf(acc[m][n][j] + bb, 0.f);
                h2[(size_t)(prow + j) * 2048 + col] = f2b(v);
            }
        }
    }
}

__global__ __launch_bounds__(256, 2)
void l3_fb(const unsigned short* __restrict__ h2, const float* __restrict__ W3,
           const int* __restrict__ perm, float* __restrict__ out)
{
    __shared__ __align__(16) unsigned short As[BM][LDSW_FB];
    __shared__ __align__(16) unsigned short Bt[BN][LDSW_FB];

    const int t = threadIdx.x;
    const int rbase = blockIdx.y * BM;
    const int cbase = blockIdx.x * BN;
    const int srow_t = t >> 3;
    const int scol   = (t & 7) * 4;

    f32x4 acc[4][4];
#pragma unroll
    for (int m = 0; m < 4; m++)
#pragma unroll
        for (int n = 0; n < 4; n++) acc[m][n] = (f32x4){0.f, 0.f, 0.f, 0.f};

    const int lane = t & 63;
    const int wid  = t >> 6;
    const int wr = wid >> 1, wc = wid & 1;
    const int lr = lane & 15;
    const int kb = (lane >> 4) * 8;

    for (int k0 = 0; k0 < 2048; k0 += BK) {
        __syncthreads();
#pragma unroll
        for (int rr = 0; rr < 4; rr++) {
            const int row = rr * 32 + srow_t;
            ushort4 av = *(const ushort4*)(h2 + (size_t)(rbase + row) * 2048 + k0 + scol);
            *(ushort4*)&As[row][scol] = av;
            float4 bv = *(const float4*)(W3 + (size_t)(cbase + row) * 2048 + k0 + scol);
            ushort4 pb;
            pb.x = f2b(bv.x); pb.y = f2b(bv.y); pb.z = f2b(bv.z); pb.w = f2b(bv.w);
            *(ushort4*)&Bt[row][scol] = pb;
        }
        __syncthreads();

        short8 af[4], bf[4];
#pragma unroll
        for (int m = 0; m < 4; m++)
            af[m] = *(const short8*)&As[wr * 64 + m * 16 + lr][kb];
#pragma unroll
        for (int n = 0; n < 4; n++)
            bf[n] = *(const short8*)&Bt[wc * 64 + n * 16 + lr][kb];
#pragma unroll
        for (int m = 0; m < 4; m++)
#pragma unroll
            for (int n = 0; n < 4; n++)
                acc[m][n] = __builtin_amdgcn_mfma_f32_16x16x32_bf16(
                    af[m], bf[n], acc[m][n], 0, 0, 0);
    }

    const int rowoff = (lane >> 4) * 4;
#pragma unroll
    for (int m = 0; m < 4; m++) {
        const int prow = rbase + wr * 64 + m * 16 + rowoff;
#pragma unroll
        for (int n = 0; n < 4; n++) {
            const int col = cbase + wc * 64 + n * 16 + lr;
#pragma unroll
            for (int j = 0; j < 4; j++) {
                int orow = perm[prow + j];
                if (orow >= 0)
                    out[(size_t)orow * 1024 + col] = acc[m][n][j];
            }
        }
    }
}

// ---------------------------------------------------------------------------
extern "C" void kernel_launch(void* const* d_in, const int* in_sizes, int n_in,
                              void* d_out, int out_size, void* d_ws, size_t ws_size,
                              hipStream_t stream)
{
    const float* x   = (const float*)d_in[0];
    const int*   gid = (const int*)d_in[1];
    const float* W1  = (const float*)d_in[2];
    const float* b1  = (const float*)d_in[3];
    const float* W2  = (const float*)d_in[4];
    const float* b2  = (const float*)d_in[5];
    const float* W3  = (const float*)d_in[6];
    float* out = (float*)d_out;
    char* ws = (char*)d_ws;

    auto alignup = [](size_t v) { return (v + 255) & ~(size_t)255; };

    // ---- big (fast-path) layout ----
    size_t off = 0;
    const size_t perm_off = off; off = alignup(off + (size_t)NP * 4);
    const size_t tg_off   = off; off = alignup(off + (size_t)NROWT * 4);
    const size_t xbf_off  = off; off = alignup(off + (size_t)4097 * 1024 * 2);
    const size_t w1_off   = off; off = alignup(off + (size_t)36864 * 1024 * 2);
    const size_t w2_off   = off; off = alignup(off + (size_t)2048 * 4096 * 2);
    const size_t w3_off   = off; off = alignup(off + (size_t)1024 * 2048 * 2);
    const size_t sB_off   = off; off = alignup(off + (size_t)NP * 4096 * 2);
    const size_t h2B_off  = off; off = alignup(off + (size_t)NP * 2048 * 2);
    const size_t need_big = off;

    // ---- small (fallback) layout (round-2 verified) ----
    const size_t sS_off   = 32768;
    const size_t h2S_off  = sS_off + (size_t)NP * 4096 * 2;
    const size_t need_sm  = h2S_off + (size_t)NP * 2048 * 2;

    int* perm = (int*)(ws + perm_off);
    int* tile_gate = (int*)(ws + tg_off);

    if (ws_size >= need_big) {
        unsigned short* xbf  = (unsigned short*)(ws + xbf_off);
        unsigned short* w1bf = (unsigned short*)(ws + w1_off);
        unsigned short* w2bf = (unsigned short*)(ws + w2_off);
        unsigned short* w3bf = (unsigned short*)(ws + w3_off);
        unsigned short* s_perm = (unsigned short*)(ws + sB_off);
        unsigned short* h2 = (unsigned short*)(ws + h2B_off);
        unsigned short* zrow = xbf + (size_t)NROWS * 1024;   // row 4096

        bucket_kernel<<<1, 256, 0, stream>>>(gid, perm, tile_gate, zrow);
        cast_kernel<<<2048, 256, 0, stream>>>(x,  xbf,  (NROWS * 1024) / 8);
        cast_kernel<<<2048, 256, 0, stream>>>(W1, w1bf, (36864 * 1024) / 8);
        cast_kernel<<<2048, 256, 0, stream>>>(W2, w2bf, (2048 * 4096) / 8);
        cast_kernel<<<1024, 256, 0, stream>>>(W3, w3bf, (1024 * 2048) / 8);
        l1_fast<<<dim3(32, NROWT), 256, 0, stream>>>(xbf, w1bf, b1, perm, tile_gate, s_perm);
        l2_fast<<<dim3(16, NROWT), 256, 0, stream>>>(s_perm, w2bf, b2, h2);
        l3_fast<<<dim3(8, NROWT), 256, 0, stream>>>(h2, w3bf, perm, out);
    } else if (ws_size >= need_sm) {
        // fallback: round-2 path, perm/tg at same offsets (0 / 20480)
        unsigned short* s_perm = (unsigned short*)(ws + sS_off);
        unsigned short* h2 = (unsigned short*)(ws + h2S_off);

        bucket_kernel<<<1, 256, 0, stream>>>(gid, perm, tile_gate, (unsigned short*)nullptr);
        l1_fb<<<dim3(32, NROWT), 256, 0, stream>>>(x, W1, b1, perm, tile_gate, s_perm);
        l2_fb<<<dim3(16, NROWT), 256, 0, stream>>>(s_perm, W2, b2, h2);
        l3_fb<<<dim3(8, NROWT), 256, 0, stream>>>(h2, W3, perm, out);
    }
    // else: ws too small even for fallback -> loud failure
}